// Round 4
// baseline (202.923 us; speedup 1.0000x reference)
//
#include <hip/hip_runtime.h>

// BurstSnn: 32-step burst-encoder + 2-layer LIF SNN, B=16384, D=187, H=50, C=5.
// One wave per batch element; 16 waves/block share one LDS weight copy.
// R3: (a) masks pinned to VGPRs -> bit-scan on VALU (4x wider than the CU's
// single SALU); (b) paired time-steps: half-wave 0 gathers step t rows,
// half-wave 1 step t+1, h packed as float2 {h, h+25} over 25 lanes ->
// ds_read_b64 delivers TWO weight rows per LDS issue. Zero rows every 32 dims
// make empty-mask iterations exact no-ops (+0.0f). Per-(b,h,t) accumulation
// remains strictly ascending-d => bitwise-identical to verified R0-R2.

constexpr int D = 187;
constexpr int H = 50;
constexpr int C = 5;
constexpr int T = 32;
constexpr int WPB = 16;        // waves per block
constexpr int ROWS1 = 193;     // 187 weight rows + zero rows at rd = 33*g
constexpr int RS = 64;         // floats per Wt1 row (256 B)

__device__ __forceinline__ unsigned int pin_v(unsigned int x) {
    asm("" : "+v"(x));         // launder to VGPR: downstream bit-ops go VALU
    return x;
}
__device__ __forceinline__ unsigned long long pin_v64(unsigned long long m) {
    unsigned int lo = (unsigned int)m, hi = (unsigned int)(m >> 32);
    asm("" : "+v"(lo));
    asm("" : "+v"(hi));
    return ((unsigned long long)hi << 32) | lo;
}

__global__ __launch_bounds__(1024, 8)
void burst_snn_kernel(const float* __restrict__ x,
                      const float* __restrict__ W1,
                      const float* __restrict__ W2,
                      float* __restrict__ out, int B) {
    // Wt1 row rd: dims d -> rd = 33*(d>>5) + (d&31) + 1; rd = 33*g are zero rows.
    // Row layout (split-pair): floats {2l,2l+1} = {W[h=l], W[h=l+25]}, l<25; rest 0.
    __shared__ float Wt1[ROWS1 * RS];   // 12352 floats = 48.25 KB
    __shared__ float Wt2[512];          // row rh = h+1 (8 floats each), rh=0 zeros

    const int tid = threadIdx.x;
    for (int idx = tid; idx < ROWS1 * RS; idx += 1024) {
        int rd = idx >> 6, j = idx & 63;
        int g = rd / 33;
        bool zrow = (rd == 33 * g);
        int d = rd - 1 - g;
        int l = j >> 1;
        int h = (j & 1) ? (l + 25) : l;
        float v = 0.f;
        if (!zrow && l < 25) v = W1[h * D + d];
        Wt1[idx] = v;
    }
    if (tid < 512) {
        int rh = tid >> 3, c = tid & 7;
        float v = 0.f;
        if (rh >= 1 && rh <= H && c < C) v = W2[c * H + (rh - 1)];
        Wt2[tid] = v;
    }
    __syncthreads();

    const int lane = tid & 63;
    const int b = blockIdx.x * WPB + (tid >> 6);
    const bool active = b < B;
    const bool isLo = lane < 32;
    const int laneHalf = lane & 31;
    const int laneOff2 = laneHalf * 2;   // float2 slot within a Wt1 row

    // Encoder registers: dims lane, lane+64, lane+128 (3rd valid for lane<59)
    float r0 = 0.f, r1 = 0.f, r2 = 0.f;
    if (active) {
        const float* xb = x + (size_t)b * D;
        r0 = xb[lane];
        r1 = xb[64 + lane];
        if (lane < D - 128) r2 = xb[128 + lane];
    }
    float th0 = 0.125f, th1 = 0.125f, th2 = 0.125f;
    float mem1x = 0.f, mem1y = 0.f;  // lanes 0..24: h = lane / h = lane+25
    float mem2 = 0.f;                // lanes 0..4: c = lane
    int cnt = 0;

    float* outSpk = out;                     // [T][B][C]
    float* outCnt = out + (size_t)T * B * C; // [B]

    unsigned int ga[6], gb[6];

    for (int t = 0; t < T; t += 2) {
        // --- two encoder steps (exact fp32 sequence), masks for t and t+1
        {
            bool s0 = r0 >= th0, s1 = r1 >= th1, s2 = r2 >= th2;
            r0 -= s0 ? th0 : 0.f; th0 = s0 ? th0 + th0 : 0.125f;
            r1 -= s1 ? th1 : 0.f; th1 = s1 ? th1 + th1 : 0.125f;
            r2 -= s2 ? th2 : 0.f; th2 = s2 ? th2 + th2 : 0.125f;
            cnt += (int)s0 + (int)s1 + (int)s2;
            unsigned long long B0 = __ballot(s0), B1 = __ballot(s1), B2 = __ballot(s2);
            ga[0] = (unsigned int)B0; ga[1] = (unsigned int)(B0 >> 32);
            ga[2] = (unsigned int)B1; ga[3] = (unsigned int)(B1 >> 32);
            ga[4] = (unsigned int)B2; ga[5] = (unsigned int)(B2 >> 32);
        }
        {
            bool s0 = r0 >= th0, s1 = r1 >= th1, s2 = r2 >= th2;
            r0 -= s0 ? th0 : 0.f; th0 = s0 ? th0 + th0 : 0.125f;
            r1 -= s1 ? th1 : 0.f; th1 = s1 ? th1 + th1 : 0.125f;
            r2 -= s2 ? th2 : 0.f; th2 = s2 ? th2 + th2 : 0.125f;
            cnt += (int)s0 + (int)s1 + (int)s2;
            unsigned long long B0 = __ballot(s0), B1 = __ballot(s1), B2 = __ballot(s2);
            gb[0] = (unsigned int)B0; gb[1] = (unsigned int)(B0 >> 32);
            gb[2] = (unsigned int)B1; gb[3] = (unsigned int)(B1 >> 32);
            gb[4] = (unsigned int)B2; gb[5] = (unsigned int)(B2 >> 32);
        }

        // --- layer-1 paired gather: lanes<32 accumulate step t, lanes>=32 step t+1
        float cx = 0.f, cy = 0.f;
#pragma unroll
        for (int g = 0; g < 6; ++g) {
            int na = __popc(ga[g]), nb = __popc(gb[g]);        // SALU trip count
            int n = na > nb ? na : nb;
            unsigned int vma = pin_v(ga[g]), vmb = pin_v(gb[g]); // VALU-side masks
            const int basem1 = 33 * g;   // rd = basem1 + __ffs(m); empty -> zero row
            for (; n > 0; --n) {
                int fa = __ffs(vma);     // 0 when empty -> rd = 33g (zeros)
                int fb = __ffs(vmb);
                vma &= vma - 1;
                vmb &= vmb - 1;
                int f = isLo ? fa : fb;
                int ii = ((f + basem1) << 6) + laneOff2;
                float2 w = *(const float2*)&Wt1[ii];
                cx += w.x;
                cy += w.y;
            }
        }
        float c1x = cx, c1y = cy;                      // step t   (lanes 0..24)
        float c2x = __shfl_down(cx, 32);               // step t+1 -> lanes 0..24
        float c2y = __shfl_down(cy, 32);

        // --- LIF layer 1, step t (ops identical in form to verified R2)
        mem1x = 0.9f * mem1x + c1x;
        bool spx = (mem1x - 1.0f > 0.f) && (lane < 25);
        mem1x -= spx ? 1.0f : 0.f;
        mem1y = 0.9f * mem1y + c1y;
        bool spy = (mem1y - 1.0f > 0.f) && (lane < 25);
        mem1y -= spy ? 1.0f : 0.f;
        unsigned long long bx = __ballot(spx), by = __ballot(spy);
        unsigned long long mh_t = (bx & 0x1FFFFFFull) | ((by & 0x1FFFFFFull) << 25);
        // --- LIF layer 1, step t+1
        mem1x = 0.9f * mem1x + c2x;
        bool qx = (mem1x - 1.0f > 0.f) && (lane < 25);
        mem1x -= qx ? 1.0f : 0.f;
        mem1y = 0.9f * mem1y + c2y;
        bool qy = (mem1y - 1.0f > 0.f) && (lane < 25);
        mem1y -= qy ? 1.0f : 0.f;
        bx = __ballot(qx); by = __ballot(qy);
        unsigned long long mh_u = (bx & 0x1FFFFFFull) | ((by & 0x1FFFFFFull) << 25);

        // --- layer-2 paired gather: rh = __ffsll(mask); empty -> row 0 (zeros)
        int n2a = __popcll(mh_t), n2b = __popcll(mh_u);
        int n2 = n2a > n2b ? n2a : n2b;
        unsigned long long va2 = pin_v64(mh_t), vb2 = pin_v64(mh_u);
        float cur2 = 0.f;
        for (; n2 > 0; --n2) {
            int fa = (int)__ffsll((unsigned long long)va2);
            int fb = (int)__ffsll((unsigned long long)vb2);
            va2 &= va2 - 1;
            vb2 &= vb2 - 1;
            int f = isLo ? fa : fb;
            cur2 += Wt2[(f << 3) + laneHalf];
        }
        float c2t1 = __shfl_down(cur2, 32);            // step t+1 -> lanes 0..4

        // --- LIF layer 2, step t
        mem2 = 0.9f * mem2 + cur2;
        bool sp2 = (mem2 - 1.0f > 0.f);
        mem2 -= sp2 ? 1.0f : 0.f;
        if (active && lane < C)
            outSpk[(size_t)t * B * C + (size_t)b * C + lane] = sp2 ? 1.0f : 0.0f;
        // --- LIF layer 2, step t+1
        mem2 = 0.9f * mem2 + c2t1;
        bool sp2b = (mem2 - 1.0f > 0.f);
        mem2 -= sp2b ? 1.0f : 0.f;
        if (active && lane < C)
            outSpk[(size_t)(t + 1) * B * C + (size_t)b * C + lane] = sp2b ? 1.0f : 0.0f;
    }

    // --- reduce spike count across the wave, write counts[b]
    for (int o = 32; o; o >>= 1) cnt += __shfl_xor(cnt, o, 64);
    if (active && lane == 0) outCnt[b] = (float)cnt;
}

extern "C" void kernel_launch(void* const* d_in, const int* in_sizes, int n_in,
                              void* d_out, int out_size, void* d_ws, size_t ws_size,
                              hipStream_t stream) {
    const float* x  = (const float*)d_in[0];
    const float* W1 = (const float*)d_in[1];
    const float* W2 = (const float*)d_in[2];
    float* out = (float*)d_out;
    const int B = in_sizes[0] / D;
    const int blocks = (B + WPB - 1) / WPB;
    burst_snn_kernel<<<blocks, 1024, 0, stream>>>(x, W1, W2, out, B);
}

// Round 5
// 182.760 us; speedup vs baseline: 1.1103x; 1.1103x over previous
//
#include <hip/hip_runtime.h>

// BurstSnn: 32-step burst-encoder + 2-layer LIF SNN, B=16384, D=187, H=50, C=5.
// One wave per batch element; 16 waves/block share one LDS weight copy.
// R4 = R3's validated time-paired dataflow (half-wave t / half-wave t+1,
// float2-packed rows {h, h+25}, ds_read_b64, zero rows at rd=33g) with a
// rebalanced pipe assignment learned from R3's VALU saturation:
//  - bit scans via inline-asm v_ffbl_b32 (defined -1 on empty mask),
//  - +1 row offset FOLDED into the per-group base (empty -> -1 -> zero row),
//  - 8 VALU instr per trip (2 ffbl, 2x2 clear... cndmask, lshl_add, 2 adds),
//  - trip counts (popc/max) + loop control on SALU.
// Summation per (b,h,t) remains strictly ascending-d fp32 => bit-identical
// to the verified R0-R3 kernels (absmax 0.0).

constexpr int D = 187;
constexpr int H = 50;
constexpr int C = 5;
constexpr int T = 32;
constexpr int WPB = 16;        // waves per block
constexpr int ROWS1 = 193;     // rows rd = 33*(d>>5) + (d&31) + 1; rd=33g zero
constexpr int RS = 64;         // floats per Wt1 row (256 B)

__device__ __forceinline__ unsigned int pin_v(unsigned int x) {
    asm("" : "+v"(x));         // launder to VGPR: downstream bit-ops go VALU
    return x;
}
__device__ __forceinline__ unsigned long long pin_v64(unsigned long long m) {
    unsigned int lo = (unsigned int)m, hi = (unsigned int)(m >> 32);
    asm("" : "+v"(lo));
    asm("" : "+v"(hi));
    return ((unsigned long long)hi << 32) | lo;
}
__device__ __forceinline__ int ffbl(unsigned int m) {  // -1 when m == 0
    int r;
    asm("v_ffbl_b32 %0, %1" : "=v"(r) : "v"(m));
    return r;
}

__global__ __launch_bounds__(1024, 8)
void burst_snn_kernel(const float* __restrict__ x,
                      const float* __restrict__ W1,
                      const float* __restrict__ W2,
                      float* __restrict__ out, int B) {
    // Row layout (split-pair): floats {2l,2l+1} = {W[h=l], W[h=l+25]}, l<25; rest 0.
    __shared__ float Wt1[ROWS1 * RS];   // 12352 floats = 48.25 KB
    __shared__ float Wt2[512];          // row rh = h+1 (8 floats each), rh=0 zeros

    const int tid = threadIdx.x;
    for (int idx = tid; idx < ROWS1 * RS; idx += 1024) {
        int rd = idx >> 6, j = idx & 63;
        int g = rd / 33;
        bool zrow = (rd == 33 * g);
        int d = rd - 1 - g;
        int l = j >> 1;
        int h = (j & 1) ? (l + 25) : l;
        float v = 0.f;
        if (!zrow && l < 25) v = W1[h * D + d];
        Wt1[idx] = v;
    }
    if (tid < 512) {
        int rh = tid >> 3, c = tid & 7;
        float v = 0.f;
        if (rh >= 1 && rh <= H && c < C) v = W2[c * H + (rh - 1)];
        Wt2[tid] = v;
    }
    __syncthreads();

    const int lane = tid & 63;
    const int b = blockIdx.x * WPB + (tid >> 6);
    const bool active = b < B;
    const bool isLo = lane < 32;
    const int laneHalf = lane & 31;
    const int laneOff2 = laneHalf * 2;   // float2 slot within a Wt1 row

    // Per-group base pointers with the +1 row offset folded in:
    // addr(f) = gbase + f*64 floats; f = -1 (empty) -> zero row 33g.
    const float* gb0 = Wt1 + ((33 * 0 + 1) << 6) + laneOff2;
    const float* gb1 = Wt1 + ((33 * 1 + 1) << 6) + laneOff2;
    const float* gb2 = Wt1 + ((33 * 2 + 1) << 6) + laneOff2;
    const float* gb3 = Wt1 + ((33 * 3 + 1) << 6) + laneOff2;
    const float* gb4 = Wt1 + ((33 * 4 + 1) << 6) + laneOff2;
    const float* gb5 = Wt1 + ((33 * 5 + 1) << 6) + laneOff2;
    const float* gbase[6] = {gb0, gb1, gb2, gb3, gb4, gb5};

    // Encoder registers: dims lane, lane+64, lane+128 (3rd valid for lane<59)
    float r0 = 0.f, r1 = 0.f, r2 = 0.f;
    if (active) {
        const float* xb = x + (size_t)b * D;
        r0 = xb[lane];
        r1 = xb[64 + lane];
        if (lane < D - 128) r2 = xb[128 + lane];
    }
    float th0 = 0.125f, th1 = 0.125f, th2 = 0.125f;
    float mem1x = 0.f, mem1y = 0.f;  // lanes 0..24: h = lane / h = lane+25
    float mem2 = 0.f;                // lanes 0..4: c = lane
    int cnt = 0;

    float* outSpk = out;                     // [T][B][C]
    float* outCnt = out + (size_t)T * B * C; // [B]

    unsigned int ga[6], gb[6];

    for (int t = 0; t < T; t += 2) {
        // --- two encoder steps (exact fp32 sequence), masks for t and t+1
        {
            bool s0 = r0 >= th0, s1 = r1 >= th1, s2 = r2 >= th2;
            r0 -= s0 ? th0 : 0.f; th0 = s0 ? th0 + th0 : 0.125f;
            r1 -= s1 ? th1 : 0.f; th1 = s1 ? th1 + th1 : 0.125f;
            r2 -= s2 ? th2 : 0.f; th2 = s2 ? th2 + th2 : 0.125f;
            cnt += (int)s0 + (int)s1 + (int)s2;
            unsigned long long B0 = __ballot(s0), B1 = __ballot(s1), B2 = __ballot(s2);
            ga[0] = (unsigned int)B0; ga[1] = (unsigned int)(B0 >> 32);
            ga[2] = (unsigned int)B1; ga[3] = (unsigned int)(B1 >> 32);
            ga[4] = (unsigned int)B2; ga[5] = (unsigned int)(B2 >> 32);
        }
        {
            bool s0 = r0 >= th0, s1 = r1 >= th1, s2 = r2 >= th2;
            r0 -= s0 ? th0 : 0.f; th0 = s0 ? th0 + th0 : 0.125f;
            r1 -= s1 ? th1 : 0.f; th1 = s1 ? th1 + th1 : 0.125f;
            r2 -= s2 ? th2 : 0.f; th2 = s2 ? th2 + th2 : 0.125f;
            cnt += (int)s0 + (int)s1 + (int)s2;
            unsigned long long B0 = __ballot(s0), B1 = __ballot(s1), B2 = __ballot(s2);
            gb[0] = (unsigned int)B0; gb[1] = (unsigned int)(B0 >> 32);
            gb[2] = (unsigned int)B1; gb[3] = (unsigned int)(B1 >> 32);
            gb[4] = (unsigned int)B2; gb[5] = (unsigned int)(B2 >> 32);
        }

        // --- layer-1 paired gather: lanes<32 accumulate step t, lanes>=32 step t+1
        float cx = 0.f, cy = 0.f;
#pragma unroll
        for (int g = 0; g < 6; ++g) {
            int na = __popc(ga[g]), nb = __popc(gb[g]);  // SALU trip count
            int n = na > nb ? na : nb;
            unsigned int vma = pin_v(ga[g]), vmb = pin_v(gb[g]);
            const float* base = gbase[g];
            for (; n > 0; --n) {
                int fa = ffbl(vma);      // -1 when empty -> zero row
                int fb = ffbl(vmb);
                vma &= vma - 1;
                vmb &= vmb - 1;
                int f = isLo ? fa : fb;                     // v_cndmask
                float2 w = *(const float2*)(base + (f << 6)); // v_lshl_add + ds_read_b64
                cx += w.x;
                cy += w.y;
            }
        }
        float c1x = cx, c1y = cy;                      // step t   (lanes 0..24)
        float c2x = __shfl_down(cx, 32);               // step t+1 -> lanes 0..24
        float c2y = __shfl_down(cy, 32);

        // --- LIF layer 1, step t
        mem1x = 0.9f * mem1x + c1x;
        bool spx = (mem1x - 1.0f > 0.f) && (lane < 25);
        mem1x -= spx ? 1.0f : 0.f;
        mem1y = 0.9f * mem1y + c1y;
        bool spy = (mem1y - 1.0f > 0.f) && (lane < 25);
        mem1y -= spy ? 1.0f : 0.f;
        unsigned long long bx = __ballot(spx), by = __ballot(spy);
        unsigned long long mh_t = (bx & 0x1FFFFFFull) | ((by & 0x1FFFFFFull) << 25);
        // --- LIF layer 1, step t+1
        mem1x = 0.9f * mem1x + c2x;
        bool qx = (mem1x - 1.0f > 0.f) && (lane < 25);
        mem1x -= qx ? 1.0f : 0.f;
        mem1y = 0.9f * mem1y + c2y;
        bool qy = (mem1y - 1.0f > 0.f) && (lane < 25);
        mem1y -= qy ? 1.0f : 0.f;
        bx = __ballot(qx); by = __ballot(qy);
        unsigned long long mh_u = (bx & 0x1FFFFFFull) | ((by & 0x1FFFFFFull) << 25);

        // --- layer-2 paired gather: rh = __ffsll(mask); empty -> row 0 (zeros)
        int n2a = __popcll(mh_t), n2b = __popcll(mh_u);
        int n2 = n2a > n2b ? n2a : n2b;
        unsigned long long va2 = pin_v64(mh_t), vb2 = pin_v64(mh_u);
        float cur2 = 0.f;
        for (; n2 > 0; --n2) {
            int fa = (int)__ffsll((unsigned long long)va2);
            int fb = (int)__ffsll((unsigned long long)vb2);
            va2 &= va2 - 1;
            vb2 &= vb2 - 1;
            int f = isLo ? fa : fb;
            cur2 += Wt2[(f << 3) + laneHalf];
        }
        float c2t1 = __shfl_down(cur2, 32);            // step t+1 -> lanes 0..4

        // --- LIF layer 2, step t
        mem2 = 0.9f * mem2 + cur2;
        bool sp2 = (mem2 - 1.0f > 0.f);
        mem2 -= sp2 ? 1.0f : 0.f;
        if (active && lane < C)
            outSpk[(size_t)t * B * C + (size_t)b * C + lane] = sp2 ? 1.0f : 0.0f;
        // --- LIF layer 2, step t+1
        mem2 = 0.9f * mem2 + c2t1;
        bool sp2b = (mem2 - 1.0f > 0.f);
        mem2 -= sp2b ? 1.0f : 0.f;
        if (active && lane < C)
            outSpk[(size_t)(t + 1) * B * C + (size_t)b * C + lane] = sp2b ? 1.0f : 0.0f;
    }

    // --- reduce spike count across the wave, write counts[b]
    for (int o = 32; o; o >>= 1) cnt += __shfl_xor(cnt, o, 64);
    if (active && lane == 0) outCnt[b] = (float)cnt;
}

extern "C" void kernel_launch(void* const* d_in, const int* in_sizes, int n_in,
                              void* d_out, int out_size, void* d_ws, size_t ws_size,
                              hipStream_t stream) {
    const float* x  = (const float*)d_in[0];
    const float* W1 = (const float*)d_in[1];
    const float* W2 = (const float*)d_in[2];
    float* out = (float*)d_out;
    const int B = in_sizes[0] / D;
    const int blocks = (B + WPB - 1) / WPB;
    burst_snn_kernel<<<blocks, 1024, 0, stream>>>(x, W1, W2, out, B);
}

// Round 6
// 171.270 us; speedup vs baseline: 1.1848x; 1.0671x over previous
//
#include <hip/hip_runtime.h>

// BurstSnn: 32-step burst-encoder + 2-layer LIF SNN, B=16384, D=187, H=50, C=5.
// One wave per batch element; 16 waves/block share one LDS weight copy.
// R5 = R4's verified time-paired dataflow (half-wave t / t+1, float2 rows
// {h=l, h=l+25}, ds_read_b64, zero rows at rd=33g, absmax 0.0) with the
// layer-1 scan SPLIT across pipes (lesson of R2=SALU-wall / R4=VALU-wall):
//   step-t mask    -> SALU scan: s_ff1_i32_b32 + scalar clear (~5 SALU/trip)
//   step-t+1 mask  -> VALU scan: v_ffbl_b32 + vector clear   (~4 VALU/trip)
//   merge: one v_cndmask (SGPR src0) + v_lshl_add address.
// Layer-2 scan stays R4's all-VALU code (64-bit scalar clears would re-create
// the SALU wall). Empty (group,pair) iterations are skipped.

constexpr int D = 187;
constexpr int H = 50;
constexpr int C = 5;
constexpr int T = 32;
constexpr int WPB = 16;        // waves per block
constexpr int ROWS1 = 193;     // rows rd = 33*(d>>5) + (d&31) + 1; rd=33g zero
constexpr int RS = 64;         // floats per Wt1 row (256 B)

__device__ __forceinline__ unsigned int pin_v(unsigned int x) {
    asm("" : "+v"(x));         // launder to VGPR: downstream bit-ops go VALU
    return x;
}
__device__ __forceinline__ unsigned long long pin_v64(unsigned long long m) {
    unsigned int lo = (unsigned int)m, hi = (unsigned int)(m >> 32);
    asm("" : "+v"(lo));
    asm("" : "+v"(hi));
    return ((unsigned long long)hi << 32) | lo;
}
__device__ __forceinline__ int v_ffbl(unsigned int m) {  // -1 when m == 0
    int r;
    asm("v_ffbl_b32 %0, %1" : "=v"(r) : "v"(m));
    return r;
}
__device__ __forceinline__ int s_ff1(unsigned int m) {   // -1 when m == 0 (SALU)
    int r;
    asm("s_ff1_i32_b32 %0, %1" : "=s"(r) : "s"(m));
    return r;
}

__global__ __launch_bounds__(1024, 8)
void burst_snn_kernel(const float* __restrict__ x,
                      const float* __restrict__ W1,
                      const float* __restrict__ W2,
                      float* __restrict__ out, int B) {
    // Row layout (split-pair): floats {2l,2l+1} = {W[h=l], W[h=l+25]}, l<25; rest 0.
    __shared__ float Wt1[ROWS1 * RS];   // 12352 floats = 48.25 KB
    __shared__ float Wt2[512];          // row rh = h+1 (8 floats each), rh=0 zeros

    const int tid = threadIdx.x;
    for (int idx = tid; idx < ROWS1 * RS; idx += 1024) {
        int rd = idx >> 6, j = idx & 63;
        int g = rd / 33;
        bool zrow = (rd == 33 * g);
        int d = rd - 1 - g;
        int l = j >> 1;
        int h = (j & 1) ? (l + 25) : l;
        float v = 0.f;
        if (!zrow && l < 25) v = W1[h * D + d];
        Wt1[idx] = v;
    }
    if (tid < 512) {
        int rh = tid >> 3, c = tid & 7;
        float v = 0.f;
        if (rh >= 1 && rh <= H && c < C) v = W2[c * H + (rh - 1)];
        Wt2[tid] = v;
    }
    __syncthreads();

    const int lane = tid & 63;
    const int b = blockIdx.x * WPB + (tid >> 6);
    const bool active = b < B;
    const bool isLo = lane < 32;
    const int laneHalf = lane & 31;
    const int laneOff2 = laneHalf * 2;   // float2 slot within a Wt1 row

    // Per-group base pointers with the +1 row offset folded in:
    // addr(f) = gbase + f*64 floats; f = -1 (empty) -> zero row 33g.
    const float* gb0 = Wt1 + ((33 * 0 + 1) << 6) + laneOff2;
    const float* gb1 = Wt1 + ((33 * 1 + 1) << 6) + laneOff2;
    const float* gb2 = Wt1 + ((33 * 2 + 1) << 6) + laneOff2;
    const float* gb3 = Wt1 + ((33 * 3 + 1) << 6) + laneOff2;
    const float* gb4 = Wt1 + ((33 * 4 + 1) << 6) + laneOff2;
    const float* gb5 = Wt1 + ((33 * 5 + 1) << 6) + laneOff2;
    const float* gbase[6] = {gb0, gb1, gb2, gb3, gb4, gb5};

    // Encoder registers: dims lane, lane+64, lane+128 (3rd valid for lane<59)
    float r0 = 0.f, r1 = 0.f, r2 = 0.f;
    if (active) {
        const float* xb = x + (size_t)b * D;
        r0 = xb[lane];
        r1 = xb[64 + lane];
        if (lane < D - 128) r2 = xb[128 + lane];
    }
    float th0 = 0.125f, th1 = 0.125f, th2 = 0.125f;
    float mem1x = 0.f, mem1y = 0.f;  // lanes 0..24: h = lane / h = lane+25
    float mem2 = 0.f;                // lanes 0..4: c = lane
    int cnt = 0;

    float* outSpk = out;                     // [T][B][C]
    float* outCnt = out + (size_t)T * B * C; // [B]

    unsigned int ga[6], gb[6];

    for (int t = 0; t < T; t += 2) {
        // --- two encoder steps (exact fp32 sequence), masks for t and t+1
        {
            bool s0 = r0 >= th0, s1 = r1 >= th1, s2 = r2 >= th2;
            r0 -= s0 ? th0 : 0.f; th0 = s0 ? th0 + th0 : 0.125f;
            r1 -= s1 ? th1 : 0.f; th1 = s1 ? th1 + th1 : 0.125f;
            r2 -= s2 ? th2 : 0.f; th2 = s2 ? th2 + th2 : 0.125f;
            cnt += (int)s0 + (int)s1 + (int)s2;
            unsigned long long B0 = __ballot(s0), B1 = __ballot(s1), B2 = __ballot(s2);
            ga[0] = (unsigned int)B0; ga[1] = (unsigned int)(B0 >> 32);
            ga[2] = (unsigned int)B1; ga[3] = (unsigned int)(B1 >> 32);
            ga[4] = (unsigned int)B2; ga[5] = (unsigned int)(B2 >> 32);
        }
        {
            bool s0 = r0 >= th0, s1 = r1 >= th1, s2 = r2 >= th2;
            r0 -= s0 ? th0 : 0.f; th0 = s0 ? th0 + th0 : 0.125f;
            r1 -= s1 ? th1 : 0.f; th1 = s1 ? th1 + th1 : 0.125f;
            r2 -= s2 ? th2 : 0.f; th2 = s2 ? th2 + th2 : 0.125f;
            cnt += (int)s0 + (int)s1 + (int)s2;
            unsigned long long B0 = __ballot(s0), B1 = __ballot(s1), B2 = __ballot(s2);
            gb[0] = (unsigned int)B0; gb[1] = (unsigned int)(B0 >> 32);
            gb[2] = (unsigned int)B1; gb[3] = (unsigned int)(B1 >> 32);
            gb[4] = (unsigned int)B2; gb[5] = (unsigned int)(B2 >> 32);
        }

        // --- layer-1 paired gather: lanes<32 accumulate step t (SALU scan),
        //     lanes>=32 step t+1 (VALU scan)
        float cx = 0.f, cy = 0.f;
#pragma unroll
        for (int g = 0; g < 6; ++g) {
            unsigned int ma = ga[g], mb = gb[g];
            if ((ma | mb) == 0u) continue;           // skip-empty (late steps)
            int na = __popc(ma), nb = __popc(mb);    // SALU s_bcnt1
            int n = na > nb ? na : nb;
            unsigned int vmb = pin_v(mb);            // VALU-side mask copy
            const float* base = gbase[g];
            for (; n > 0; --n) {
                int fa = s_ff1(ma);      // SALU: -1 when empty -> zero row
                ma &= ma - 1;            // SALU clear
                int fb = v_ffbl(vmb);    // VALU: -1 when empty -> zero row
                vmb &= vmb - 1;          // VALU clear
                int f = isLo ? fa : fb;                       // v_cndmask (s,v)
                float2 w = *(const float2*)(base + (f << 6)); // v_lshl_add + ds_read_b64
                cx += w.x;
                cy += w.y;
            }
        }
        float c1x = cx, c1y = cy;                      // step t   (lanes 0..24)
        float c2x = __shfl_down(cx, 32);               // step t+1 -> lanes 0..24
        float c2y = __shfl_down(cy, 32);

        // --- LIF layer 1, step t
        mem1x = 0.9f * mem1x + c1x;
        bool spx = (mem1x - 1.0f > 0.f) && (lane < 25);
        mem1x -= spx ? 1.0f : 0.f;
        mem1y = 0.9f * mem1y + c1y;
        bool spy = (mem1y - 1.0f > 0.f) && (lane < 25);
        mem1y -= spy ? 1.0f : 0.f;
        unsigned long long bx = __ballot(spx), by = __ballot(spy);
        unsigned long long mh_t = (bx & 0x1FFFFFFull) | ((by & 0x1FFFFFFull) << 25);
        // --- LIF layer 1, step t+1
        mem1x = 0.9f * mem1x + c2x;
        bool qx = (mem1x - 1.0f > 0.f) && (lane < 25);
        mem1x -= qx ? 1.0f : 0.f;
        mem1y = 0.9f * mem1y + c2y;
        bool qy = (mem1y - 1.0f > 0.f) && (lane < 25);
        mem1y -= qy ? 1.0f : 0.f;
        bx = __ballot(qx); by = __ballot(qy);
        unsigned long long mh_u = (bx & 0x1FFFFFFull) | ((by & 0x1FFFFFFull) << 25);

        // --- layer-2 paired gather (all-VALU, as verified in R4):
        //     rh = __ffsll(mask); empty -> row 0 (zeros)
        float cur2 = 0.f;
        int n2a = __popcll(mh_t), n2b = __popcll(mh_u);
        int n2 = n2a > n2b ? n2a : n2b;
        if (n2) {
            unsigned long long va2 = pin_v64(mh_t), vb2 = pin_v64(mh_u);
            for (; n2 > 0; --n2) {
                int fa = (int)__ffsll((unsigned long long)va2);
                int fb = (int)__ffsll((unsigned long long)vb2);
                va2 &= va2 - 1;
                vb2 &= vb2 - 1;
                int f = isLo ? fa : fb;
                cur2 += Wt2[(f << 3) + laneHalf];
            }
        }
        float c2t1 = __shfl_down(cur2, 32);            // step t+1 -> lanes 0..4

        // --- LIF layer 2, step t
        mem2 = 0.9f * mem2 + cur2;
        bool sp2 = (mem2 - 1.0f > 0.f);
        mem2 -= sp2 ? 1.0f : 0.f;
        if (active && lane < C)
            outSpk[(size_t)t * B * C + (size_t)b * C + lane] = sp2 ? 1.0f : 0.0f;
        // --- LIF layer 2, step t+1
        mem2 = 0.9f * mem2 + c2t1;
        bool sp2b = (mem2 - 1.0f > 0.f);
        mem2 -= sp2b ? 1.0f : 0.f;
        if (active && lane < C)
            outSpk[(size_t)(t + 1) * B * C + (size_t)b * C + lane] = sp2b ? 1.0f : 0.0f;
    }

    // --- reduce spike count across the wave, write counts[b]
    for (int o = 32; o; o >>= 1) cnt += __shfl_xor(cnt, o, 64);
    if (active && lane == 0) outCnt[b] = (float)cnt;
}

extern "C" void kernel_launch(void* const* d_in, const int* in_sizes, int n_in,
                              void* d_out, int out_size, void* d_ws, size_t ws_size,
                              hipStream_t stream) {
    const float* x  = (const float*)d_in[0];
    const float* W1 = (const float*)d_in[1];
    const float* W2 = (const float*)d_in[2];
    float* out = (float*)d_out;
    const int B = in_sizes[0] / D;
    const int blocks = (B + WPB - 1) / WPB;
    burst_snn_kernel<<<blocks, 1024, 0, stream>>>(x, W1, W2, out, B);
}

// Round 7
// 166.341 us; speedup vs baseline: 1.2199x; 1.0296x over previous
//
#include <hip/hip_runtime.h>

// BurstSnn: 32-step burst-encoder + 2-layer LIF SNN, B=16384, D=187, H=50, C=5.
// One wave per batch element; 16 waves/block share one LDS weight copy.
// R6 = R5's verified layout/masks with the layer-1 gather restructured for
// memory-level parallelism (R5 post-mortem: no pipe saturated -> latency-bound
// with only 1 outstanding ds_read per wave):
//   2 phases x 3 CONCURRENT streams; phase0 scans u32 groups {0,2,4},
//   phase1 {1,3,5}; stream k owns accumulators for contiguous d-range k
//   (order stays ascending-d per accumulator; final (c0+c1)+c2).
//   Each iteration issues 3 independent ds_read_b64 -> lgkmcnt(2/1/0) waits.
// t/t+1 half-wave pairing retained; t-vs-t+1 mask select hoisted to one
// cndmask per stream per phase. Zero rows at rd=33g absorb exhausted streams.

constexpr int D = 187;
constexpr int H = 50;
constexpr int C = 5;
constexpr int T = 32;
constexpr int WPB = 16;        // waves per block
constexpr int ROWS1 = 193;     // rows rd = 33*(d>>5) + (d&31) + 1; rd=33g zero
constexpr int RS = 64;         // floats per Wt1 row (256 B)

__device__ __forceinline__ unsigned long long pin_v64(unsigned long long m) {
    unsigned int lo = (unsigned int)m, hi = (unsigned int)(m >> 32);
    asm("" : "+v"(lo));
    asm("" : "+v"(hi));
    return ((unsigned long long)hi << 32) | lo;
}
__device__ __forceinline__ int v_ffbl(unsigned int m) {  // -1 when m == 0
    int r;
    asm("v_ffbl_b32 %0, %1" : "=v"(r) : "v"(m));
    return r;
}

__global__ __launch_bounds__(1024, 8)
void burst_snn_kernel(const float* __restrict__ x,
                      const float* __restrict__ W1,
                      const float* __restrict__ W2,
                      float* __restrict__ out, int B) {
    // Row layout (split-pair): floats {2l,2l+1} = {W[h=l], W[h=l+25]}, l<25; rest 0.
    __shared__ float Wt1[ROWS1 * RS];   // 12352 floats = 48.25 KB
    __shared__ float Wt2[512];          // row rh = h+1 (8 floats each), rh=0 zeros

    const int tid = threadIdx.x;
    for (int idx = tid; idx < ROWS1 * RS; idx += 1024) {
        int rd = idx >> 6, j = idx & 63;
        int g = rd / 33;
        bool zrow = (rd == 33 * g);
        int d = rd - 1 - g;
        int l = j >> 1;
        int h = (j & 1) ? (l + 25) : l;
        float v = 0.f;
        if (!zrow && l < 25) v = W1[h * D + d];
        Wt1[idx] = v;
    }
    if (tid < 512) {
        int rh = tid >> 3, c = tid & 7;
        float v = 0.f;
        if (rh >= 1 && rh <= H && c < C) v = W2[c * H + (rh - 1)];
        Wt2[tid] = v;
    }
    __syncthreads();

    const int lane = tid & 63;
    const int b = blockIdx.x * WPB + (tid >> 6);
    const bool active = b < B;
    const bool isLo = lane < 32;
    const int laneHalf = lane & 31;
    const int laneOff2 = laneHalf * 2;   // float2 slot within a Wt1 row

    // Per-group base pointers with the +1 row offset folded in:
    // addr(f) = gbase + f*64 floats; f = -1 (empty) -> zero row 33g.
    const float* gbase[6] = {
        Wt1 + ((33 * 0 + 1) << 6) + laneOff2,
        Wt1 + ((33 * 1 + 1) << 6) + laneOff2,
        Wt1 + ((33 * 2 + 1) << 6) + laneOff2,
        Wt1 + ((33 * 3 + 1) << 6) + laneOff2,
        Wt1 + ((33 * 4 + 1) << 6) + laneOff2,
        Wt1 + ((33 * 5 + 1) << 6) + laneOff2,
    };

    // Encoder registers: dims lane, lane+64, lane+128 (3rd valid for lane<59)
    float r0 = 0.f, r1 = 0.f, r2 = 0.f;
    if (active) {
        const float* xb = x + (size_t)b * D;
        r0 = xb[lane];
        r1 = xb[64 + lane];
        if (lane < D - 128) r2 = xb[128 + lane];
    }
    float th0 = 0.125f, th1 = 0.125f, th2 = 0.125f;
    float mem1x = 0.f, mem1y = 0.f;  // lanes 0..24: h = lane / h = lane+25
    float mem2 = 0.f;                // lanes 0..4: c = lane
    int cnt = 0;

    float* outSpk = out;                     // [T][B][C]
    float* outCnt = out + (size_t)T * B * C; // [B]

    unsigned int ga[6], gb[6];

    for (int t = 0; t < T; t += 2) {
        // --- two encoder steps (exact fp32 sequence), masks for t and t+1
        {
            bool s0 = r0 >= th0, s1 = r1 >= th1, s2 = r2 >= th2;
            r0 -= s0 ? th0 : 0.f; th0 = s0 ? th0 + th0 : 0.125f;
            r1 -= s1 ? th1 : 0.f; th1 = s1 ? th1 + th1 : 0.125f;
            r2 -= s2 ? th2 : 0.f; th2 = s2 ? th2 + th2 : 0.125f;
            cnt += (int)s0 + (int)s1 + (int)s2;
            unsigned long long B0 = __ballot(s0), B1 = __ballot(s1), B2 = __ballot(s2);
            ga[0] = (unsigned int)B0; ga[1] = (unsigned int)(B0 >> 32);
            ga[2] = (unsigned int)B1; ga[3] = (unsigned int)(B1 >> 32);
            ga[4] = (unsigned int)B2; ga[5] = (unsigned int)(B2 >> 32);
        }
        {
            bool s0 = r0 >= th0, s1 = r1 >= th1, s2 = r2 >= th2;
            r0 -= s0 ? th0 : 0.f; th0 = s0 ? th0 + th0 : 0.125f;
            r1 -= s1 ? th1 : 0.f; th1 = s1 ? th1 + th1 : 0.125f;
            r2 -= s2 ? th2 : 0.f; th2 = s2 ? th2 + th2 : 0.125f;
            cnt += (int)s0 + (int)s1 + (int)s2;
            unsigned long long B0 = __ballot(s0), B1 = __ballot(s1), B2 = __ballot(s2);
            gb[0] = (unsigned int)B0; gb[1] = (unsigned int)(B0 >> 32);
            gb[2] = (unsigned int)B1; gb[3] = (unsigned int)(B1 >> 32);
            gb[4] = (unsigned int)B2; gb[5] = (unsigned int)(B2 >> 32);
        }

        // --- layer-1 paired gather, 2 phases x 3 concurrent streams.
        //     Stream k accumulates d-range k: phase0 groups {0,2,4},
        //     phase1 groups {1,3,5}. Lanes<32 = step t, lanes>=32 = step t+1.
        float cx0 = 0.f, cy0 = 0.f, cx1 = 0.f, cy1 = 0.f, cx2 = 0.f, cy2 = 0.f;
#pragma unroll
        for (int ph = 0; ph < 2; ++ph) {
            const int i0 = ph, i1 = 2 + ph, i2 = 4 + ph;
            unsigned int a0 = ga[i0], b0m = gb[i0];
            unsigned int a1 = ga[i1], b1m = gb[i1];
            unsigned int a2 = ga[i2], b2m = gb[i2];
            int n0 = __popc(a0) > __popc(b0m) ? __popc(a0) : __popc(b0m);
            int n1 = __popc(a1) > __popc(b1m) ? __popc(a1) : __popc(b1m);
            int n2_ = __popc(a2) > __popc(b2m) ? __popc(a2) : __popc(b2m);
            int n = n0 > n1 ? n0 : n1;
            n = n > n2_ ? n : n2_;
            if (n == 0) continue;
            unsigned int vm0 = isLo ? a0 : b0m;   // per-lane masks (VGPR)
            unsigned int vm1 = isLo ? a1 : b1m;
            unsigned int vm2 = isLo ? a2 : b2m;
            const float* base0 = gbase[i0];
            const float* base1 = gbase[i1];
            const float* base2 = gbase[i2];
            for (; n > 0; --n) {
                int f0 = v_ffbl(vm0); vm0 &= vm0 - 1;   // -1 when empty -> zero row
                int f1 = v_ffbl(vm1); vm1 &= vm1 - 1;
                int f2 = v_ffbl(vm2); vm2 &= vm2 - 1;
                float2 w0 = *(const float2*)(base0 + f0 * 64);
                float2 w1 = *(const float2*)(base1 + f1 * 64);
                float2 w2 = *(const float2*)(base2 + f2 * 64);
                cx0 += w0.x; cy0 += w0.y;
                cx1 += w1.x; cy1 += w1.y;
                cx2 += w2.x; cy2 += w2.y;
            }
        }
        float cx = (cx0 + cx1) + cx2;
        float cy = (cy0 + cy1) + cy2;
        float c1x = cx, c1y = cy;                      // step t   (lanes 0..24)
        float c2x = __shfl_down(cx, 32);               // step t+1 -> lanes 0..24
        float c2y = __shfl_down(cy, 32);

        // --- LIF layer 1, step t
        mem1x = 0.9f * mem1x + c1x;
        bool spx = (mem1x - 1.0f > 0.f) && (lane < 25);
        mem1x -= spx ? 1.0f : 0.f;
        mem1y = 0.9f * mem1y + c1y;
        bool spy = (mem1y - 1.0f > 0.f) && (lane < 25);
        mem1y -= spy ? 1.0f : 0.f;
        unsigned long long bx = __ballot(spx), by = __ballot(spy);
        unsigned long long mh_t = (bx & 0x1FFFFFFull) | ((by & 0x1FFFFFFull) << 25);
        // --- LIF layer 1, step t+1
        mem1x = 0.9f * mem1x + c2x;
        bool qx = (mem1x - 1.0f > 0.f) && (lane < 25);
        mem1x -= qx ? 1.0f : 0.f;
        mem1y = 0.9f * mem1y + c2y;
        bool qy = (mem1y - 1.0f > 0.f) && (lane < 25);
        mem1y -= qy ? 1.0f : 0.f;
        bx = __ballot(qx); by = __ballot(qy);
        unsigned long long mh_u = (bx & 0x1FFFFFFull) | ((by & 0x1FFFFFFull) << 25);

        // --- layer-2 paired gather (all-VALU, as verified in R4/R5):
        //     rh = __ffsll(mask); empty -> row 0 (zeros)
        float cur2 = 0.f;
        int n2a = __popcll(mh_t), n2b = __popcll(mh_u);
        int n2 = n2a > n2b ? n2a : n2b;
        if (n2) {
            unsigned long long va2 = pin_v64(mh_t), vb2 = pin_v64(mh_u);
            for (; n2 > 0; --n2) {
                int fa = (int)__ffsll((unsigned long long)va2);
                int fb = (int)__ffsll((unsigned long long)vb2);
                va2 &= va2 - 1;
                vb2 &= vb2 - 1;
                int f = isLo ? fa : fb;
                cur2 += Wt2[(f << 3) + laneHalf];
            }
        }
        float c2t1 = __shfl_down(cur2, 32);            // step t+1 -> lanes 0..4

        // --- LIF layer 2, step t
        mem2 = 0.9f * mem2 + cur2;
        bool sp2 = (mem2 - 1.0f > 0.f);
        mem2 -= sp2 ? 1.0f : 0.f;
        if (active && lane < C)
            outSpk[(size_t)t * B * C + (size_t)b * C + lane] = sp2 ? 1.0f : 0.0f;
        // --- LIF layer 2, step t+1
        mem2 = 0.9f * mem2 + c2t1;
        bool sp2b = (mem2 - 1.0f > 0.f);
        mem2 -= sp2b ? 1.0f : 0.f;
        if (active && lane < C)
            outSpk[(size_t)(t + 1) * B * C + (size_t)b * C + lane] = sp2b ? 1.0f : 0.0f;
    }

    // --- reduce spike count across the wave, write counts[b]
    for (int o = 32; o; o >>= 1) cnt += __shfl_xor(cnt, o, 64);
    if (active && lane == 0) outCnt[b] = (float)cnt;
}

extern "C" void kernel_launch(void* const* d_in, const int* in_sizes, int n_in,
                              void* d_out, int out_size, void* d_ws, size_t ws_size,
                              hipStream_t stream) {
    const float* x  = (const float*)d_in[0];
    const float* W1 = (const float*)d_in[1];
    const float* W2 = (const float*)d_in[2];
    float* out = (float*)d_out;
    const int B = in_sizes[0] / D;
    const int blocks = (B + WPB - 1) / WPB;
    burst_snn_kernel<<<blocks, 1024, 0, stream>>>(x, W1, W2, out, B);
}